// Round 5
// baseline (368.265 us; speedup 1.0000x reference)
//
#include <hip/hip_runtime.h>
#include <stdint.h>

#define T_TOKENS 8192
#define D_DIM 512
#define F_DIM 2048
#define E_NUM 8

typedef short short8 __attribute__((ext_vector_type(8)));
typedef float f32x4 __attribute__((ext_vector_type(4)));

// ---------------- bf16 helpers (RNE, finite inputs) -------------------------
__device__ __forceinline__ unsigned short f2bf(float f) {
    union { float f; unsigned int u; } c; c.f = f;
    unsigned int u = c.u;
    unsigned int r = (u + 0x7fffu + ((u >> 16) & 1u)) >> 16;
    return (unsigned short)r;
}
__device__ __forceinline__ unsigned int pack2(float a, float b) {
    return (unsigned int)f2bf(a) | ((unsigned int)f2bf(b) << 16);
}
// nontemporal 16B load of fp32x4 (native ext_vector works with the builtin)
__device__ __forceinline__ f32x4 ntload4(const float* p) {
    return __builtin_nontemporal_load((const f32x4*)p);
}

// ws layout (bytes)
#define WS_COUNT 0
#define WS_PROBS 512
#define WS_TOK   16384
#define WS_WGT   (WS_TOK + E_NUM * T_TOKENS * 4)
#define WS_W1B   (1u << 20)
#define WS_W2B   (WS_W1B + 16777216u)

// ---------------------------------------------------------------------------
// Convert w1/w2 fp32 -> bf16 in MFMA B-fragment order (same layout as R2):
//   frag-lane linear = ((e*(N/16) + ft)*(K/32) + ks)*64 + L
//   element = M[ks*32 + (L>>4)*8 + j][ft*16 + (L&15)]
// Also: zeroes y (2 floats/thread), count[], probs_g[] (replaces memset+init).
// ---------------------------------------------------------------------------
__global__ __launch_bounds__(256) void moe_convert(
    const float* __restrict__ w1, const float* __restrict__ w2,
    unsigned short* __restrict__ w1b, unsigned short* __restrict__ w2b,
    int* __restrict__ count, float* __restrict__ probs_g,
    float* __restrict__ y)
{
    __shared__ float ts[32][65];   // 32 k-rows x 64 n-cols (+pad)
    int tid = threadIdx.x;
    // zero y: 8192 blocks * 256 threads * 1 float2 = 4,194,304 floats = T*D
    {
        size_t gid = (size_t)blockIdx.x * 256 + tid;
        ((float2*)y)[gid] = make_float2(0.f, 0.f);
    }
    if (blockIdx.x == 0 && tid < E_NUM) { count[tid] = 0; probs_g[tid] = 0.f; }

    int b = blockIdx.x;
    bool is2 = b >= 4096;
    int o = is2 ? b - 4096 : b;
    int e = o >> 9, r = o & 511;
    int N  = is2 ? 512 : 2048;
    int Ks = is2 ? 64 : 16;
    int ng, ks;
    if (!is2) { ng = r & 31; ks = r >> 5; }
    else      { ng = r & 7;  ks = r >> 3; }

    const float* src = (is2 ? w2 : w1) + ((size_t)e << 20) + (size_t)(ks * 32) * N + ng * 64;
    int row = tid >> 3, c4 = (tid & 7) * 4;
    f32x4 v0 = *(const f32x4*)(src + (size_t)row * N + c4);
    f32x4 v1 = *(const f32x4*)(src + (size_t)row * N + c4 + 32);
    *(f32x4*)&ts[row][c4] = v0;
    *(f32x4*)&ts[row][c4 + 32] = v1;
    __syncthreads();

    int f = tid >> 6, L = tid & 63, q = L >> 4, n = L & 15;
    float v[8];
#pragma unroll
    for (int j = 0; j < 8; ++j) v[j] = ts[q * 8 + j][f * 16 + n];
    uint4 pk;
    pk.x = pack2(v[0], v[1]); pk.y = pack2(v[2], v[3]);
    pk.z = pack2(v[4], v[5]); pk.w = pack2(v[6], v[7]);
    size_t fraglane = ((size_t)((e * (N / 16) + ng * 4 + f) * Ks + ks)) * 64 + L;
    unsigned short* dst = (is2 ? w2b : w1b) + fraglane * 8;
    *(uint4*)dst = pk;
}

// ---------------------------------------------------------------------------
// Router: 256 threads = 4 waves; one WAVE per token (8 tokens/wave, looped).
// gate_w held in 64 VGPRs per lane; nontemporal coalesced x fetch; butterfly
// reduce; per-block lists, 8 list atomics + 8 prob atomics per block.
// ---------------------------------------------------------------------------
__global__ __launch_bounds__(256) void moe_router(
    const float* __restrict__ x, const float* __restrict__ gw,
    int* __restrict__ count, int* __restrict__ tok_list,
    float* __restrict__ wgt_list, float* __restrict__ probs_g)
{
    __shared__ float pprob[E_NUM];
    __shared__ int   lcnt[E_NUM];
    __shared__ int   gbase[E_NUM];
    __shared__ int   ltok[E_NUM][64];
    __shared__ float lwgt[E_NUM][64];

    int tid = threadIdx.x;
    if (tid < E_NUM) { pprob[tid] = 0.f; lcnt[tid] = 0; }
    __syncthreads();

    int wv = tid >> 6, lane = tid & 63;

    // gate weights for this lane's d-slice: gw[(lane*8+j)*8 + e] = linear lane*64 + j*8 + e
    float gr[64];
    {
        const f32x4* gp = (const f32x4*)(gw + lane * 64);
#pragma unroll
        for (int i = 0; i < 16; ++i) *(f32x4*)&gr[i * 4] = gp[i];
    }

    float wps[E_NUM];
#pragma unroll
    for (int e = 0; e < E_NUM; ++e) wps[e] = 0.f;

#pragma unroll 1
    for (int i = 0; i < 8; ++i) {
        int t = blockIdx.x * 32 + wv * 8 + i;
        const float* xp = x + (size_t)t * D_DIM + lane * 8;
        f32x4 x0 = ntload4(xp);
        f32x4 x1 = ntload4(xp + 4);
        float xv[8] = { x0.x, x0.y, x0.z, x0.w, x1.x, x1.y, x1.z, x1.w };
        float acc[E_NUM];
#pragma unroll
        for (int e = 0; e < E_NUM; ++e) acc[e] = 0.f;
#pragma unroll
        for (int j = 0; j < 8; ++j)
#pragma unroll
            for (int e = 0; e < E_NUM; ++e) acc[e] += xv[j] * gr[j * 8 + e];
        // butterfly over 64 lanes
#pragma unroll
        for (int off = 1; off < 64; off <<= 1)
#pragma unroll
            for (int e = 0; e < E_NUM; ++e) acc[e] += __shfl_xor(acc[e], off);

        float m = acc[0];
#pragma unroll
        for (int e = 1; e < E_NUM; ++e) m = fmaxf(m, acc[e]);
        float p[E_NUM], s = 0.f;
#pragma unroll
        for (int e = 0; e < E_NUM; ++e) { p[e] = __expf(acc[e] - m); s += p[e]; }
        float inv = 1.f / s;
#pragma unroll
        for (int e = 0; e < E_NUM; ++e) { p[e] *= inv; wps[e] += p[e]; }

        // top-2 (ties -> lower index)
        int e1 = 0;
#pragma unroll
        for (int e = 1; e < E_NUM; ++e) if (p[e] > p[e1]) e1 = e;
        int e2 = (e1 == 0) ? 1 : 0;
#pragma unroll
        for (int e = 0; e < E_NUM; ++e) if (e != e1 && p[e] > p[e2]) e2 = e;

        if (lane == 0) {
            float invw = 1.f / (p[e1] + p[e2]);
            int s1 = atomicAdd(&lcnt[e1], 1); ltok[e1][s1] = t; lwgt[e1][s1] = p[e1] * invw;
            int s2 = atomicAdd(&lcnt[e2], 1); ltok[e2][s2] = t; lwgt[e2][s2] = p[e2] * invw;
        }
    }
    if (lane == 0) {
#pragma unroll
        for (int e = 0; e < E_NUM; ++e) atomicAdd(&pprob[e], wps[e]);
    }
    __syncthreads();
    if (tid < E_NUM) {
        gbase[tid] = atomicAdd(&count[tid], lcnt[tid]);
        atomicAdd(&probs_g[tid], pprob[tid]);
    }
    __syncthreads();
    int ee = tid >> 5;
    for (int ss = tid & 31; ss < lcnt[ee]; ss += 32) {
        int dst = ee * T_TOKENS + gbase[ee] + ss;
        tok_list[dst] = ltok[ee][ss];
        wgt_list[dst] = lwgt[ee][ss];
    }
}

// ---------------------------------------------------------------------------
// FFN item = (expert, f-half, 64-token tile). 512 threads = 8 waves.
// bx = ((half*128 + tile)<<3)|e : e pins XCD (bx%8); half-major ordering keeps
// concurrent blocks on one XCD inside a single 2 MB weight slice (L2-resident).
// Per f-half: 4 chunks of 256 f. Pipeline:
//   A(c0);  for cc: [barrier; write hs(c); barrier; merged A(c+1)+B(c) | B(c3)]
// All weight streams use 2-deep register prefetch (~308 cyc > L2 latency).
// Block 0 also writes the load-balance loss (router ran earlier on stream).
// ---------------------------------------------------------------------------
__global__ __launch_bounds__(512, 2) void moe_ffn(
    const float* __restrict__ x,
    const unsigned short* __restrict__ w1b, const float* __restrict__ b1,
    const unsigned short* __restrict__ w2b, const float* __restrict__ b2,
    const int* __restrict__ count, const int* __restrict__ tok_list,
    const float* __restrict__ wgt_list, float* __restrict__ y,
    const float* __restrict__ probs_g)
{
    int e   = blockIdx.x & 7;
    int ht  = blockIdx.x >> 3;
    int half = ht >> 7;
    int tile = ht & 127;

    if (blockIdx.x == 0 && threadIdx.x == 0) {
        float s = 0.f;
#pragma unroll
        for (int i = 0; i < E_NUM; ++i) {
            float m = probs_g[i] / (float)T_TOKENS;
            s += m * m;
        }
        y[(size_t)T_TOKENS * D_DIM] = (float)E_NUM * s;
    }

    int cnt = count[e];
    if (tile * 64 >= cnt) return;

    __shared__ __align__(16) unsigned short Xf[64 * 64 * 8];   // 64 KB, A-frag order
    __shared__ __align__(16) unsigned short hs[64][264];       // 33.8 KB, padded
    __shared__ int   stok[64];
    __shared__ float swgt[64];

    int tid = threadIdx.x;
    if (tid < 64) {
        int s = tile * 64 + tid;
        if (s < cnt) { stok[tid] = tok_list[e * T_TOKENS + s]; swgt[tid] = wgt_list[e * T_TOKENS + s]; }
        else         { stok[tid] = 0; swgt[tid] = 0.f; }
    }
    __syncthreads();

    // ---- stage X tile into LDS in A-fragment order (nontemporal reads) -----
    {
        int tl = tid >> 3;
        int kb = (tid & 7) * 64;
        const float* xr = x + (size_t)stok[tl] * D_DIM + kb;
        int mt = tl >> 4, nn = tl & 15;
#pragma unroll
        for (int g = 0; g < 8; ++g) {
            f32x4 v0 = ntload4(xr + g * 8);
            f32x4 v1 = ntload4(xr + g * 8 + 4);
            int ka = kb + g * 8;
            int ks = ka >> 5, qq = (ka >> 3) & 3;
            uint4 pk;
            pk.x = pack2(v0.x, v0.y); pk.y = pack2(v0.z, v0.w);
            pk.z = pack2(v1.x, v1.y); pk.w = pack2(v1.z, v1.w);
            *(uint4*)&Xf[(size_t)((mt * 16 + ks) * 64 + qq * 16 + nn) * 8] = pk;
        }
    }
    __syncthreads();

    int wv = tid >> 6, lane = tid & 63;
    int q = lane >> 4, n = lane & 15;
    const short8* w1p = (const short8*)w1b;
    const short8* w2p = (const short8*)w2b;

    int c0 = half * 4;

    f32x4 aA[2][4];
    f32x4 aB[4][4];
#pragma unroll
    for (int a = 0; a < 4; ++a)
#pragma unroll
        for (int b = 0; b < 4; ++b) aB[a][b] = (f32x4){0.f, 0.f, 0.f, 0.f};

    // ---- prologue: A(c0), 2-deep prefetch ----------------------------------
    {
#pragma unroll
        for (int a = 0; a < 2; ++a)
#pragma unroll
            for (int b = 0; b < 4; ++b) aA[a][b] = (f32x4){0.f, 0.f, 0.f, 0.f};
        size_t w1L = ((size_t)((e * 128 + c0 * 16 + wv * 2) * 16)) * 64 + lane;
        short8 s0a = w1p[w1L],      s0b = w1p[w1L + 1024];
        short8 s1a = w1p[w1L + 64], s1b = w1p[w1L + 64 + 1024];
#pragma unroll 2
        for (int ks = 0; ks < 16; ++ks) {
            short8 cw0 = s0a, cw1 = s0b;
            s0a = s1a; s0b = s1b;
            int kp = (ks + 2 < 16) ? ks + 2 : 15;
            s1a = w1p[w1L + kp * 64]; s1b = w1p[w1L + kp * 64 + 1024];
#pragma unroll
            for (int mt = 0; mt < 4; ++mt) {
                short8 a = *(const short8*)&Xf[(size_t)((mt * 16 + ks) * 64 + lane) * 8];
                aA[0][mt] = __builtin_amdgcn_mfma_f32_16x16x32_bf16(a, cw0, aA[0][mt], 0, 0, 0);
                aA[1][mt] = __builtin_amdgcn_mfma_f32_16x16x32_bf16(a, cw1, aA[1][mt], 0, 0, 0);
            }
        }
    }

    // ---- main: epilogue(c) then merged A(c+1)+B(c) (or drain B on last) ----
#pragma unroll 1
    for (int cc = 0; cc < 4; ++cc) {
        int c = c0 + cc;
        __syncthreads();   // previous B readers done with hs
        // write hs(c) = gelu(aA + b1)
#pragma unroll
        for (int nt = 0; nt < 2; ++nt) {
            int fg = (c * 16 + wv * 2 + nt) * 16 + n;
            float bb = b1[e * F_DIM + fg];
            int fl = (wv * 2 + nt) * 16 + n;
#pragma unroll
            for (int mt = 0; mt < 4; ++mt)
#pragma unroll
                for (int r = 0; r < 4; ++r) {
                    float h = aA[nt][mt][r] + bb;
                    h = 0.5f * h * (1.f + erff(h * 0.70710678118654752440f));
                    hs[mt * 16 + q * 4 + r][fl] = f2bf(h);
                }
        }
        __syncthreads();   // hs(c) ready

        size_t w2L = ((size_t)((e * 32 + wv * 4) * 64) + c * 8) * 64 + lane;
        short8 aH[4];

        if (cc < 3) {
            // merged: A(c+1) + B(c), 2-deep prefetch of all 4 weight streams
#pragma unroll
            for (int a = 0; a < 2; ++a)
#pragma unroll
                for (int b = 0; b < 4; ++b) aA[a][b] = (f32x4){0.f, 0.f, 0.f, 0.f};
            size_t w1L = ((size_t)((e * 128 + (c + 1) * 16 + wv * 2) * 16)) * 64 + lane;
            short8 p0w0 = w1p[w1L],      p0w1 = w1p[w1L + 1024];
            short8 p1w0 = w1p[w1L + 64], p1w1 = w1p[w1L + 64 + 1024];
            short8 p0a = w2p[w2L],        p0b = w2p[w2L + 4096];
            short8 p1a = w2p[w2L + 8192], p1b = w2p[w2L + 8192 + 4096];
#pragma unroll 2
            for (int it = 0; it < 16; ++it) {
                short8 cw0 = p0w0, cw1 = p0w1, c2a = p0a, c2b = p0b;
                p0w0 = p1w0; p0w1 = p1w1; p0a = p1a; p0b = p1b;
                int itp = (it + 2 < 16) ? it + 2 : 15;
                p1w0 = w1p[w1L + itp * 64];
                p1w1 = w1p[w1L + itp * 64 + 1024];
                size_t o2 = w2L + (size_t)(itp >> 1) * 64 + (size_t)(itp & 1) * 8192;
                p1a = w2p[o2]; p1b = w2p[o2 + 4096];

                if ((it & 1) == 0) {
                    int ks2 = it >> 1;
#pragma unroll
                    for (int mt = 0; mt < 4; ++mt)
                        aH[mt] = *(const short8*)&hs[mt * 16 + n][ks2 * 32 + q * 8];
                }
#pragma unroll
                for (int mt = 0; mt < 4; ++mt) {
                    short8 a = *(const short8*)&Xf[(size_t)((mt * 16 + it) * 64 + lane) * 8];
                    aA[0][mt] = __builtin_amdgcn_mfma_f32_16x16x32_bf16(a, cw0, aA[0][mt], 0, 0, 0);
                    aA[1][mt] = __builtin_amdgcn_mfma_f32_16x16x32_bf16(a, cw1, aA[1][mt], 0, 0, 0);
                }
                int nt0 = (it & 1) * 2;
#pragma unroll
                for (int mt = 0; mt < 4; ++mt)
                    aB[nt0][mt] = __builtin_amdgcn_mfma_f32_16x16x32_bf16(aH[mt], c2a, aB[nt0][mt], 0, 0, 0);
#pragma unroll
                for (int mt = 0; mt < 4; ++mt)
                    aB[nt0 + 1][mt] = __builtin_amdgcn_mfma_f32_16x16x32_bf16(aH[mt], c2b, aB[nt0 + 1][mt], 0, 0, 0);
            }
        } else {
            // drain: B(c3) only, 2-deep prefetch
            short8 p0a = w2p[w2L],        p0b = w2p[w2L + 4096];
            short8 p1a = w2p[w2L + 8192], p1b = w2p[w2L + 8192 + 4096];
#pragma unroll 2
            for (int it = 0; it < 16; ++it) {
                short8 c2a = p0a, c2b = p0b;
                p0a = p1a; p0b = p1b;
                int itp = (it + 2 < 16) ? it + 2 : 15;
                size_t o2 = w2L + (size_t)(itp >> 1) * 64 + (size_t)(itp & 1) * 8192;
                p1a = w2p[o2]; p1b = w2p[o2 + 4096];

                if ((it & 1) == 0) {
                    int ks2 = it >> 1;
#pragma unroll
                    for (int mt = 0; mt < 4; ++mt)
                        aH[mt] = *(const short8*)&hs[mt * 16 + n][ks2 * 32 + q * 8];
                }
                int nt0 = (it & 1) * 2;
#pragma unroll
                for (int mt = 0; mt < 4; ++mt)
                    aB[nt0][mt] = __builtin_amdgcn_mfma_f32_16x16x32_bf16(aH[mt], c2a, aB[nt0][mt], 0, 0, 0);
#pragma unroll
                for (int mt = 0; mt < 4; ++mt)
                    aB[nt0 + 1][mt] = __builtin_amdgcn_mfma_f32_16x16x32_bf16(aH[mt], c2b, aB[nt0 + 1][mt], 0, 0, 0);
            }
        }
    }

    // ---- final epilogue: y += wgt * (out + b2 [half 0 only]) ---------------
#pragma unroll
    for (int nt = 0; nt < 4; ++nt) {
        int d = wv * 64 + nt * 16 + n;
        float bb = (half == 0) ? b2[e * D_DIM + d] : 0.f;
#pragma unroll
        for (int mt = 0; mt < 4; ++mt)
#pragma unroll
            for (int r = 0; r < 4; ++r) {
                int m = mt * 16 + q * 4 + r;
                float wg = swgt[m];
                if (wg != 0.f)
                    atomicAdd(y + (size_t)stok[m] * D_DIM + d, wg * (aB[nt][mt][r] + bb));
            }
    }
}

// ---------------------------------------------------------------------------
extern "C" void kernel_launch(void* const* d_in, const int* in_sizes, int n_in,
                              void* d_out, int out_size, void* d_ws, size_t ws_size,
                              hipStream_t stream) {
    const float* x  = (const float*)d_in[0];
    const float* gw = (const float*)d_in[1];
    const float* w1 = (const float*)d_in[2];
    const float* b1 = (const float*)d_in[3];
    const float* w2 = (const float*)d_in[4];
    const float* b2 = (const float*)d_in[5];
    float* out = (float*)d_out;

    char* ws = (char*)d_ws;
    int*   count     = (int*)(ws + WS_COUNT);
    float* probs_g   = (float*)(ws + WS_PROBS);
    int*   tok_list  = (int*)(ws + WS_TOK);
    float* wgt_list  = (float*)(ws + WS_WGT);
    unsigned short* w1b = (unsigned short*)(ws + WS_W1B);
    unsigned short* w2b = (unsigned short*)(ws + WS_W2B);

    moe_convert<<<8192, 256, 0, stream>>>(w1, w2, w1b, w2b, count, probs_g, out);
    moe_router<<<T_TOKENS / 32, 256, 0, stream>>>(x, gw, count, tok_list, wgt_list, probs_g);
    moe_ffn<<<E_NUM * 2 * 128, 512, 0, stream>>>(x, w1b, b1, w2b, b2, count, tok_list, wgt_list, out, probs_g);
}